// Round 10
// baseline (1543.924 us; speedup 1.0000x reference)
//
#include <hip/hip_runtime.h>
#include <hip/hip_bf16.h>
#include <math.h>

#define N_NODES_C 50000
#define N_EDGES_C 800000
#define NFEAT_C 512
#define NH_C 128
#define NLAYERS_C 16

typedef __attribute__((ext_vector_type(8))) short short8;
typedef __attribute__((ext_vector_type(4))) float f32x4;

__device__ __forceinline__ float b2f(unsigned short h) {
    union { unsigned int u; float f; } v; v.u = ((unsigned int)h) << 16; return v.f;
}
__device__ __forceinline__ unsigned short f2b(float f) {
    union { float f; unsigned int u; } v; v.f = f;
    unsigned int r = (v.u + 0x7fffu + ((v.u >> 16) & 1u)) >> 16;
    return (unsigned short)r;
}

// ---------------- CSR build (int32 [2,E], validated by R3≡R5≡R6 bit-identity) --

__global__ __launch_bounds__(256) void k_count(const int* __restrict__ row,
                                               int* __restrict__ cnt) {
    int e = blockIdx.x * 256 + threadIdx.x;
    atomicAdd(&cnt[row[e]], 1);
}

__global__ __launch_bounds__(256) void k_scan1(const int* __restrict__ cnt,
                                               int* __restrict__ locex,
                                               int* __restrict__ partials, int n) {
    __shared__ int sm[256];
    int t = threadIdx.x;
    int i = blockIdx.x * 256 + t;
    int v = (i < n) ? cnt[i] : 0;
    sm[t] = v;
    __syncthreads();
    for (int o = 1; o < 256; o <<= 1) {
        int x = (t >= o) ? sm[t - o] : 0;
        __syncthreads();
        sm[t] += x;
        __syncthreads();
    }
    if (i < n) locex[i] = sm[t] - v;
    if (t == 255) partials[blockIdx.x] = sm[255];
}

__global__ __launch_bounds__(256) void k_scan2(int* __restrict__ partials, int np) {
    __shared__ int sm[256];
    int t = threadIdx.x;
    int v = (t < np) ? partials[t] : 0;
    sm[t] = v;
    __syncthreads();
    for (int o = 1; o < 256; o <<= 1) {
        int x = (t >= o) ? sm[t - o] : 0;
        __syncthreads();
        sm[t] += x;
        __syncthreads();
    }
    if (t < np) partials[t] = sm[t] - v;
}

__global__ __launch_bounds__(256) void k_scan3(const int* __restrict__ cnt,
                                               const int* __restrict__ locex,
                                               const int* __restrict__ partials,
                                               int* __restrict__ rowptr,
                                               int* __restrict__ cursor,
                                               float* __restrict__ dinv,
                                               int n, int ne) {
    int i = blockIdx.x * 256 + threadIdx.x;
    if (i < n) {
        int rp = locex[i] + partials[i >> 8];
        rowptr[i] = rp;
        cursor[i] = rp;
        dinv[i] = 1.0f / sqrtf((float)(cnt[i] + 1));  // +1 self loop
    }
    if (i == 0) rowptr[n] = ne;
}

__global__ __launch_bounds__(256) void k_fill(const int* __restrict__ row,
                                              const int* __restrict__ col,
                                              int* __restrict__ cursor,
                                              int* __restrict__ colsorted) {
    int e = blockIdx.x * 256 + threadIdx.x;
    int p = atomicAdd(&cursor[row[e]], 1);
    colsorted[p] = col[e];
}

// ---------------- weight conversion fp32 -> internal bf16 ----------------

__global__ __launch_bounds__(256) void k_convw(const float* __restrict__ src,
                                               unsigned short* __restrict__ dst, int n) {
    int i = blockIdx.x * 256 + threadIdx.x;
    if (i < n) dst[i] = f2b(src[i]);
}

// ---------------- SpMM + support fusion (validated ≡ scatter in R6) -----------
// s[r] = 0.9*dinv[r]*(sum_c hs[c] + hs[r]) + 0.1*h0[r],  hs = dinv .* h

__global__ __launch_bounds__(256) void k_spmm(const unsigned short* __restrict__ hs,
                                              const unsigned short* __restrict__ h0,
                                              const float* __restrict__ dinv,
                                              const int* __restrict__ rowptr,
                                              const int* __restrict__ cols,
                                              unsigned short* __restrict__ sout) {
    const int w = threadIdx.x >> 6, ln = threadIdx.x & 63;
    const int r = blockIdx.x * 4 + w;
    const unsigned int* hsu = (const unsigned int*)hs;
    unsigned int su = hsu[(size_t)r * 64 + ln];  // self loop
    float a0 = b2f((unsigned short)(su & 0xffffu));
    float a1 = b2f((unsigned short)(su >> 16));
    int e = rowptr[r];
    const int end = rowptr[r + 1];
    for (; e + 1 < end; e += 2) {
        int c0 = cols[e], c1 = cols[e + 1];
        unsigned int u0 = hsu[(size_t)c0 * 64 + ln];
        unsigned int u1 = hsu[(size_t)c1 * 64 + ln];
        a0 += b2f((unsigned short)(u0 & 0xffffu)) + b2f((unsigned short)(u1 & 0xffffu));
        a1 += b2f((unsigned short)(u0 >> 16)) + b2f((unsigned short)(u1 >> 16));
    }
    if (e < end) {
        int c = cols[e];
        unsigned int u = hsu[(size_t)c * 64 + ln];
        a0 += b2f((unsigned short)(u & 0xffffu));
        a1 += b2f((unsigned short)(u >> 16));
    }
    float dr = 0.9f * dinv[r];
    unsigned int hu = ((const unsigned int*)h0)[(size_t)r * 64 + ln];
    float s0 = dr * a0 + 0.1f * b2f((unsigned short)(hu & 0xffffu));
    float s1 = dr * a1 + 0.1f * b2f((unsigned short)(hu >> 16));
    ((unsigned int*)sout)[(size_t)r * 64 + ln] =
        (unsigned int)f2b(s0) | ((unsigned int)f2b(s1) << 16);
}

// ---------------- MFMA GEMM: C[M,128] = A[M,K] @ B[K,128] ---------------------
// A: fp32 x (AFP32=1) or internal bf16 (AFP32=0). B: internal bf16. bias: fp32.
// mode 0 (fc0):  v=relu(acc+bias[n]); out1=v (h0, bf16); out0=v*dinv[r] (hs, bf16)
// mode 1 (layer):v=relu(theta*acc+(1-theta)*S[r,n]); out0=v*(use_dinv?dinv[r]:1)
// mode 2 (fc1):  v=acc+bias[n]; outf=v  (FP32 — the reference's output dtype)

#define LDB 136

template <int AFP32>
__global__ __launch_bounds__(256) void k_gemm(
    const void* __restrict__ Av, const unsigned short* __restrict__ B,
    int M, int K,
    const float* __restrict__ bias, const unsigned short* __restrict__ S,
    const float* __restrict__ dinv,
    unsigned short* __restrict__ out0, unsigned short* __restrict__ out1,
    float* __restrict__ outf,
    int mode, float theta, int use_dinv) {
    __shared__ __align__(16) unsigned short bt[128 * LDB];
    const int tid = threadIdx.x;
    const int w = tid >> 6, ln = tid & 63;
    const int quad = ln >> 4, l16 = ln & 15;
    const int m_base = blockIdx.x * 128 + w * 32;

    f32x4 acc[2][8];
#pragma unroll
    for (int i = 0; i < 2; i++)
#pragma unroll
        for (int j = 0; j < 8; j++) acc[i][j] = (f32x4){0.f, 0.f, 0.f, 0.f};

    for (int kc = 0; kc < K; kc += 128) {
        // stage B[kc..kc+128][0..128] (bf16) transposed into LDS
        for (int idx = tid; idx < 128 * 64; idx += 256) {
            int k = idx >> 6;
            int nh = idx & 63;
            unsigned int u = ((const unsigned int*)B)[(size_t)(kc + k) * 64 + nh];
            bt[(2 * nh) * LDB + k] = (unsigned short)(u & 0xffffu);
            bt[(2 * nh + 1) * LDB + k] = (unsigned short)(u >> 16);
        }
        __syncthreads();
#pragma unroll
        for (int ki = 0; ki < 128; ki += 32) {
            short8 bf[8];
#pragma unroll
            for (int nt = 0; nt < 8; nt++)
                bf[nt] = *(const short8*)&bt[(nt * 16 + l16) * LDB + ki + quad * 8];
#pragma unroll
            for (int mt = 0; mt < 2; mt++) {
                int row = m_base + mt * 16 + l16;
                if (row >= M) row = M - 1;
                short8 af;
                if (AFP32) {
                    const float* A = (const float*)Av;
                    const float* p = &A[(size_t)row * K + kc + ki + quad * 8];
                    float4 f0 = *(const float4*)p;
                    float4 f1 = *(const float4*)(p + 4);
                    af[0] = (short)f2b(f0.x); af[1] = (short)f2b(f0.y);
                    af[2] = (short)f2b(f0.z); af[3] = (short)f2b(f0.w);
                    af[4] = (short)f2b(f1.x); af[5] = (short)f2b(f1.y);
                    af[6] = (short)f2b(f1.z); af[7] = (short)f2b(f1.w);
                } else {
                    const unsigned short* A = (const unsigned short*)Av;
                    af = *(const short8*)&A[(size_t)row * K + kc + ki + quad * 8];
                }
#pragma unroll
                for (int nt = 0; nt < 8; nt++)
                    acc[mt][nt] = __builtin_amdgcn_mfma_f32_16x16x32_bf16(
                        af, bf[nt], acc[mt][nt], 0, 0, 0);
            }
        }
        __syncthreads();
    }

    // epilogue: C/D layout col=l16, row=quad*4+reg (verified m89/m91)
#pragma unroll
    for (int mt = 0; mt < 2; mt++) {
        int rb = m_base + mt * 16 + quad * 4;
#pragma unroll
        for (int reg = 0; reg < 4; reg++) {
            int r = rb + reg;
            if (r >= M) continue;
            size_t base = (size_t)r * NH_C;
            float dr = (mode != 2) ? dinv[r] : 1.f;
#pragma unroll
            for (int nt = 0; nt < 8; nt++) {
                int n = nt * 16 + l16;
                float v = acc[mt][nt][reg];
                if (mode == 0) {
                    v += bias[n];
                    v = fmaxf(v, 0.f);
                    out1[base + n] = f2b(v);
                    out0[base + n] = f2b(v * dr);
                } else if (mode == 1) {
                    float s = b2f(S[base + n]);
                    v = theta * v + (1.f - theta) * s;
                    v = fmaxf(v, 0.f);
                    out0[base + n] = f2b(use_dinv ? v * dr : v);
                } else {
                    v += bias[n];
                    outf[base + n] = v;   // FP32 output — reference dtype
                }
            }
        }
    }
}

// ---------------- host ----------------

extern "C" void kernel_launch(void* const* d_in, const int* in_sizes, int n_in,
                              void* d_out, int out_size, void* d_ws, size_t ws_size,
                              hipStream_t stream) {
    // dict-order binding, all-fp32 inputs, int32 [2,E] edges:
    // proven by R1 signature + R3≡R5 (positional≡by-size) + R6/R7 in-band tests.
    const float* x = (const float*)d_in[0];
    const int* edge = (const int*)d_in[1];
    const float* convw = (const float*)d_in[2];
    const float* fc0w = (const float*)d_in[3];
    const float* fc0b = (const float*)d_in[4];
    const float* fc1w = (const float*)d_in[5];
    const float* fc1b = (const float*)d_in[6];
    const int* erow = edge;
    const int* ecol = edge + N_EDGES_C;

    char* ws = (char*)d_ws;
    size_t off = 0;
    auto alloc = [&](size_t bytes) -> void* {
        off = (off + 255) & ~(size_t)255;
        void* p = ws + off;
        off += bytes;
        return p;
    };
    int* cnt = (int*)alloc(N_NODES_C * 4);
    int* cursor = (int*)alloc(N_NODES_C * 4);
    int* locex = (int*)alloc(N_NODES_C * 4);
    int* partials = (int*)alloc(1024);
    int* rowptr = (int*)alloc((N_NODES_C + 1) * 4);
    float* dinv = (float*)alloc(N_NODES_C * 4);
    int* colsorted = (int*)alloc(N_EDGES_C * 4);
    unsigned short* wconv = (unsigned short*)alloc((size_t)NLAYERS_C * NH_C * NH_C * 2);
    unsigned short* wfc0 = (unsigned short*)alloc((size_t)NFEAT_C * NH_C * 2);
    unsigned short* wfc1 = (unsigned short*)alloc((size_t)NH_C * NH_C * 2);
    unsigned short* h0 = (unsigned short*)alloc((size_t)N_NODES_C * NH_C * 2);
    unsigned short* hs = (unsigned short*)alloc((size_t)N_NODES_C * NH_C * 2);
    unsigned short* sbuf = (unsigned short*)alloc((size_t)N_NODES_C * NH_C * 2);
    (void)ws_size; (void)n_in; (void)in_sizes; (void)out_size;

    // weights -> internal bf16
    k_convw<<<NLAYERS_C * NH_C * NH_C / 256, 256, 0, stream>>>(
        convw, wconv, NLAYERS_C * NH_C * NH_C);
    k_convw<<<NFEAT_C * NH_C / 256, 256, 0, stream>>>(fc0w, wfc0, NFEAT_C * NH_C);
    k_convw<<<NH_C * NH_C / 256, 256, 0, stream>>>(fc1w, wfc1, NH_C * NH_C);

    // CSR build
    hipMemsetAsync(cnt, 0, N_NODES_C * 4, stream);
    k_count<<<N_EDGES_C / 256, 256, 0, stream>>>(erow, cnt);
    const int NB = (N_NODES_C + 255) / 256;  // 196
    k_scan1<<<NB, 256, 0, stream>>>(cnt, locex, partials, N_NODES_C);
    k_scan2<<<1, 256, 0, stream>>>(partials, NB);
    k_scan3<<<NB, 256, 0, stream>>>(cnt, locex, partials, rowptr, cursor, dinv,
                                    N_NODES_C, N_EDGES_C);
    k_fill<<<N_EDGES_C / 256, 256, 0, stream>>>(erow, ecol, cursor, colsorted);

    const int GB = (N_NODES_C + 127) / 128;  // 391
    // fc0: h0 = relu(x@fc0_w + b); hs = dinv .* h0   (13 args)
    k_gemm<1><<<GB, 256, 0, stream>>>(x, wfc0, N_NODES_C, NFEAT_C, fc0b, nullptr, dinv,
                                      hs, h0, nullptr, 0, 0.f, 1);
    for (int l = 0; l < NLAYERS_C; l++) {
        k_spmm<<<N_NODES_C / 4, 256, 0, stream>>>(hs, h0, dinv, rowptr, colsorted, sbuf);
        float theta = logf(0.5f / (float)(l + 1) + 1.0f);
        // 13 args: Av, B, M, K, bias, S, dinv, out0, out1, outf, mode, theta, use_dinv
        k_gemm<0><<<GB, 256, 0, stream>>>(sbuf, wconv + (size_t)l * NH_C * NH_C,
                                          N_NODES_C, NH_C, nullptr, sbuf, dinv, hs,
                                          nullptr, nullptr, 1, theta,
                                          (l < NLAYERS_C - 1) ? 1 : 0);
    }
    // fc1: out = h@fc1_w + b  -> FP32 output  (13 args)
    k_gemm<0><<<GB, 256, 0, stream>>>(hs, wfc1, N_NODES_C, NH_C, fc1b, nullptr, nullptr,
                                      nullptr, nullptr, (float*)d_out, 2, 0.f, 0);
}